// Round 1
// baseline (82.705 us; speedup 1.0000x reference)
//
#include <hip/hip_runtime.h>

#define NB 8
#define LC 512
#define LQ 64
#define DD 256
#define NEG_BIG_F 1e30f

#define RPB 16            // rows per block
#define RPW 4             // rows per wave
#define BPB (LC / RPB)    // blocks per batch = 32

// Broadcast a float from `lane` to all lanes as a wave-uniform (SGPR) value.
#if __has_builtin(__builtin_amdgcn_readlane)
__device__ __forceinline__ float bcastf(float x, int lane) {
  return __uint_as_float((unsigned)__builtin_amdgcn_readlane((int)__float_as_uint(x), lane));
}
#else
__device__ __forceinline__ float bcastf(float x, int lane) {
  return __shfl(x, lane, 64);
}
#endif

__global__ __launch_bounds__(256) void rows_kernel(
    const float* __restrict__ context,   // [NB][LC][DD]
    const float* __restrict__ question,  // [NB][LQ][DD]
    const int*   __restrict__ mask,      // [NB][LQ]
    const float* __restrict__ att_w,     // [3*DD]
    const float* __restrict__ att_b,     // [1]
    const float* __restrict__ w_in,      // [DD]
    const float* __restrict__ w_mem,     // [DD]
    float* __restrict__ out,             // [NB][LC][4]
    float* __restrict__ ws)              // m[NB*LC], c1[NB*LC], U[NB*LC]
{
  // qs4[c][j] = question[b][j][4c..4c+3]  (transposed-by-chunks layout:
  // lane j reads qs4[c][j] -> consecutive 16B -> conflict-free ds_read_b128)
  __shared__ float4 qs4[64][64];                 // 64 KiB
  __shared__ float sq_part[LQ][4];
  __shared__ float q1_part[LQ][4];
  __shared__ float sqm[LQ];
  __shared__ float q1s[LQ];

  const int tid  = threadIdx.x;
  const int b    = blockIdx.x / BPB;
  const int row0 = (blockIdx.x % BPB) * RPB;

  // ---- pre-phase: stage question[b] into LDS, compute sq[j]+bias+mask, q1[j]
  {
    const int j  = tid >> 2;       // 0..63
    const int dq = tid & 3;        // d-range [dq*64, dq*64+64)
    const float4* qrow = (const float4*)(question + ((size_t)b * LQ + j) * DD + dq * 64);
    const float4* wq   = (const float4*)(att_w + DD + dq * 64);
    const float4* wm   = (const float4*)(w_mem + dq * 64);
    float psq = 0.f, pq1 = 0.f;
#pragma unroll
    for (int k = 0; k < 16; ++k) {
      float4 v = qrow[k];
      float4 a = wq[k];
      float4 c = wm[k];
      psq += v.x*a.x + v.y*a.y + v.z*a.z + v.w*a.w;
      pq1 += v.x*c.x + v.y*c.y + v.z*c.z + v.w*c.w;
      qs4[dq*16 + k][j] = v;
    }
    sq_part[j][dq] = psq;
    q1_part[j][dq] = pq1;
  }
  __syncthreads();
  if (tid < LQ) {
    const int j = tid;
    float sq = sq_part[j][0] + sq_part[j][1] + sq_part[j][2] + sq_part[j][3] + att_b[0];
    float mf = (float)mask[b * LQ + j];
    sqm[j] = sq - NEG_BIG_F * (1.0f - mf);
    q1s[j] = q1_part[j][0] + q1_part[j][1] + q1_part[j][2] + q1_part[j][3];
  }
  __syncthreads();

  // ---- main phase: wave w handles rows i0..i0+RPW-1, lane l = column j
  const int w  = tid >> 6;
  const int l  = tid & 63;
  const int i0 = row0 + w * RPW;

  const float4 wc4 = ((const float4*)att_w)[l];
  const float4 wp4 = ((const float4*)(att_w + 2 * DD))[l];
  const float4 wi4 = ((const float4*)w_in)[l];

  float4 cp[RPW];
  float sc[RPW], c1[RPW];
#pragma unroll
  for (int r = 0; r < RPW; ++r) {
    float4 c4 = ((const float4*)(context + ((size_t)b * LC + i0 + r) * DD))[l];
    sc[r] = c4.x*wc4.x + c4.y*wc4.y + c4.z*wc4.z + c4.w*wc4.w;
    c1[r] = c4.x*wi4.x + c4.y*wi4.y + c4.z*wi4.z + c4.w*wi4.w;
    cp[r].x = c4.x*wp4.x; cp[r].y = c4.y*wp4.y; cp[r].z = c4.z*wp4.z; cp[r].w = c4.w*wp4.w;
  }
  // wave-reduce sc (scores' context term) and c1 (ctx1) for each row
#pragma unroll
  for (int off = 32; off > 0; off >>= 1) {
#pragma unroll
    for (int r = 0; r < RPW; ++r) {
      sc[r] += __shfl_xor(sc[r], off);
      c1[r] += __shfl_xor(c1[r], off);
    }
  }

  // sp[i_r][j]: lane j accumulates over d; ctx broadcast from lane c via readlane
  float acc[RPW] = {0.f, 0.f, 0.f, 0.f};
#pragma unroll 8
  for (int c = 0; c < 64; ++c) {
    float4 qv = qs4[c][l];
#pragma unroll
    for (int r = 0; r < RPW; ++r) {
      acc[r] += bcastf(cp[r].x, c) * qv.x
              + bcastf(cp[r].y, c) * qv.y
              + bcastf(cp[r].z, c) * qv.z
              + bcastf(cp[r].w, c) * qv.w;
    }
  }

  const float sqm_l = sqm[l];
  const float q1_l  = q1s[l];
#pragma unroll
  for (int r = 0; r < RPW; ++r) {
    float v = acc[r] + sc[r] + sqm_l;     // masked attention score, lane = j
    float m = v;
#pragma unroll
    for (int off = 32; off > 0; off >>= 1) m = fmaxf(m, __shfl_xor(m, off));
    float p  = __expf(v - m);
    float ps = p;
    float pu = p * q1_l;
#pragma unroll
    for (int off = 32; off > 0; off >>= 1) {
      ps += __shfl_xor(ps, off);
      pu += __shfl_xor(pu, off);
    }
    if (l == 0) {
      const int gi = b * LC + i0 + r;
      const float U = pu / ps;
      out[gi * 4 + 0] = c1[r];
      out[gi * 4 + 1] = U;
      out[gi * 4 + 2] = c1[r] * U;
      ws[gi]               = m;      // row max of masked scores
      ws[NB * LC + gi]     = c1[r];  // ctx1
      ws[2 * NB * LC + gi] = U;
    }
  }
}

__global__ __launch_bounds__(512) void batch_kernel(
    const float* __restrict__ ws,
    float* __restrict__ out)
{
  const int b = blockIdx.x;
  const int t = threadIdx.x;          // t = row i (512 threads)
  const int gi = b * LC + t;
  const float m  = ws[gi];
  const float c1 = ws[NB * LC + gi];
  const float U  = ws[2 * NB * LC + gi];

  const int w = t >> 6, l = t & 63;
  __shared__ float rmax[8], rs[8], rc[8];

  float mx = m;
#pragma unroll
  for (int off = 32; off > 0; off >>= 1) mx = fmaxf(mx, __shfl_xor(mx, off));
  if (l == 0) rmax[w] = mx;
  __syncthreads();
  mx = rmax[0];
#pragma unroll
  for (int k = 1; k < 8; ++k) mx = fmaxf(mx, rmax[k]);

  float p  = __expf(m - mx);
  float ps = p;
  float pc = p * c1;
#pragma unroll
  for (int off = 32; off > 0; off >>= 1) {
    ps += __shfl_xor(ps, off);
    pc += __shfl_xor(pc, off);
  }
  if (l == 0) { rs[w] = ps; rc[w] = pc; }
  __syncthreads();
  float S = 0.f, C = 0.f;
#pragma unroll
  for (int k = 0; k < 8; ++k) { S += rs[k]; C += rc[k]; }

  const float H = C / S;
  out[gi * 4 + 3] = U * H;
}

extern "C" void kernel_launch(void* const* d_in, const int* in_sizes, int n_in,
                              void* d_out, int out_size, void* d_ws, size_t ws_size,
                              hipStream_t stream) {
  const float* context  = (const float*)d_in[0];
  const float* question = (const float*)d_in[1];
  const int*   mask     = (const int*)d_in[2];
  const float* att_w    = (const float*)d_in[3];
  const float* att_b    = (const float*)d_in[4];
  const float* w_in     = (const float*)d_in[5];
  const float* w_mem    = (const float*)d_in[6];
  float* out = (float*)d_out;
  float* ws  = (float*)d_ws;

  rows_kernel<<<dim3(NB * BPB), dim3(256), 0, stream>>>(
      context, question, mask, att_w, att_b, w_in, w_mem, out, ws);
  batch_kernel<<<dim3(NB), dim3(512), 0, stream>>>(ws, out);
}